// Round 2
// baseline (452.731 us; speedup 1.0000x reference)
//
#include <hip/hip_runtime.h>
#include <hip/hip_bf16.h>
#include <stdint.h>

#define T_LEN  2048
#define E_DIM  1024
#define BATCH  4
#define HEADS  16
#define HDIM   64
#define CHUNK_ 128
#define NCHUNK 16
#define EPS_   1e-6f

typedef __attribute__((ext_vector_type(8))) short bf16x8;
typedef __attribute__((ext_vector_type(4))) float f32x4;

__device__ __forceinline__ float b2f(__hip_bfloat16 h) { return __bfloat162float(h); }
__device__ __forceinline__ unsigned short f2bu(float f) {
  __hip_bfloat16 h = __float2bfloat16(f);
  return *(unsigned short*)&h;
}

// ---------------------------------------------------------------------------
// Fused fp32 -> bf16 cast for x (8192x1024) and the four 1024x1024 weights.
// One block = 1024 elements (256 threads x 4).
// ---------------------------------------------------------------------------
__global__ __launch_bounds__(256)
void cast5(const float* __restrict__ x,  const float* __restrict__ w0,
           const float* __restrict__ w1, const float* __restrict__ w2,
           const float* __restrict__ w3,
           __hip_bfloat16* __restrict__ xb,  __hip_bfloat16* __restrict__ w0b,
           __hip_bfloat16* __restrict__ w1b, __hip_bfloat16* __restrict__ w2b,
           __hip_bfloat16* __restrict__ w3b)
{
  const int b = blockIdx.x;
  const float* s;
  __hip_bfloat16* d;
  size_t off;
  if (b < 8192) {
    s = x; d = xb; off = (size_t)b * 1024;
  } else {
    const int i = (b - 8192) >> 10;
    const int r = (b - 8192) & 1023;
    s = (i == 0) ? w0 : (i == 1) ? w1 : (i == 2) ? w2 : w3;
    d = (i == 0) ? w0b : (i == 1) ? w1b : (i == 2) ? w2b : w3b;
    off = (size_t)r * 1024;
  }
  const int t = threadIdx.x;
  float4 v = *(const float4*)(s + off + (size_t)t * 4);
  ushort4 o;
  o.x = f2bu(v.x); o.y = f2bu(v.y); o.z = f2bu(v.z); o.w = f2bu(v.w);
  *(ushort4*)((unsigned short*)d + off + (size_t)t * 4) = o;
}

// ---------------------------------------------------------------------------
// GEMM: C[m,n] = act( sum_k X[m,k] * W[n,k] [+ bias[n]] )
// X: [M,K] bf16 row-major; W: [N,K] bf16 row-major.
// mode 0: identity (bf16 out), 1: elu(x)+1 (bf16 out), 2: +bias (fp32 out)
// 64x64 tile, BK=32, 4 waves: wave w owns rows [w*16, w*16+16) x 64 cols.
// ---------------------------------------------------------------------------
__global__ __launch_bounds__(256)
void gemm_nt(const __hip_bfloat16* __restrict__ X,
             const __hip_bfloat16* __restrict__ W,
             const float* __restrict__ bias,
             void* __restrict__ Cout,
             int M, int N, int K, int mode)
{
  constexpr int LDK = 40;  // 32 + 8 pad elements (80 B row stride, 16B-aligned)
  __shared__ __align__(16) __hip_bfloat16 Xs[64 * LDK];
  __shared__ __align__(16) __hip_bfloat16 Ws[64 * LDK];
  const int t    = threadIdx.x;
  const int lane = t & 63;
  const int wave = t >> 6;
  const int bm = blockIdx.x, bn = blockIdx.y;

  f32x4 acc[4];
#pragma unroll
  for (int i = 0; i < 4; ++i) acc[i] = (f32x4){0.f, 0.f, 0.f, 0.f};

  const int lrow = t >> 2;          // 0..63
  const int lcol = (t & 3) << 3;    // 0,8,16,24
  const __hip_bfloat16* Xg = X + (size_t)(bm * 64 + lrow) * K + lcol;
  const __hip_bfloat16* Wg = W + (size_t)(bn * 64 + lrow) * K + lcol;
  const int fr = lane & 15;         // fragment row
  const int fk = (lane >> 4) << 3;  // fragment k offset

  for (int k0 = 0; k0 < K; k0 += 32) {
    uint4 xv = *(const uint4*)(Xg + k0);
    uint4 wv = *(const uint4*)(Wg + k0);
    *(uint4*)&Xs[lrow * LDK + lcol] = xv;
    *(uint4*)&Ws[lrow * LDK + lcol] = wv;
    __syncthreads();
    bf16x8 a = *(const bf16x8*)&Xs[(wave * 16 + fr) * LDK + fk];
#pragma unroll
    for (int nt = 0; nt < 4; ++nt) {
      bf16x8 b = *(const bf16x8*)&Ws[(nt * 16 + fr) * LDK + fk];
      acc[nt] = __builtin_amdgcn_mfma_f32_16x16x32_bf16(a, b, acc[nt], 0, 0, 0);
    }
    __syncthreads();
  }

  // C/D layout: col = lane&15, row = (lane>>4)*4 + reg  [verified m89/m91]
  const int cm = wave * 16 + ((lane >> 4) << 2);
  const int cn = lane & 15;
#pragma unroll
  for (int nt = 0; nt < 4; ++nt) {
    int n = bn * 64 + nt * 16 + cn;
    float bv = (mode == 2) ? bias[n] : 0.f;
#pragma unroll
    for (int r = 0; r < 4; ++r) {
      float vacc = acc[nt][r] + bv;
      if (mode == 1) vacc = (vacc > 0.f) ? (vacc + 1.f) : __expf(vacc);  // elu+1
      size_t idx = (size_t)(bm * 64 + cm + r) * N + n;
      if (mode == 2) ((float*)Cout)[idx] = vacc;
      else           ((__hip_bfloat16*)Cout)[idx] = __float2bfloat16(vacc);
    }
  }
}

// ---------------------------------------------------------------------------
// Per-chunk KV state: kv[d,e] = sum_c phik[c,d]*v[c,e]; zk[d] = sum_c phik[c,d]
// One block per (b,h,n). Thread t computes a 4x4 sub-block.
// ---------------------------------------------------------------------------
__global__ __launch_bounds__(256)
void chunk_kv(const __hip_bfloat16* __restrict__ Kp,
              const __hip_bfloat16* __restrict__ Vp,
              float* __restrict__ kvout, float* __restrict__ zkout)
{
  const int bid = blockIdx.x;  // b*256 + h*16 + n
  const int n = bid & 15, h = (bid >> 4) & 15, b = bid >> 8;
  __shared__ __align__(16) __hip_bfloat16 ks[CHUNK_ * HDIM];
  __shared__ __align__(16) __hip_bfloat16 vs[CHUNK_ * HDIM];
  const size_t base = ((size_t)(b * T_LEN + n * CHUNK_)) * E_DIM + h * HDIM;
  const int t = threadIdx.x;
  for (int i = t; i < CHUNK_ * 8; i += 256) {
    int r = i >> 3, c = (i & 7) << 3;
    *(uint4*)&ks[r * HDIM + c] = *(const uint4*)(Kp + base + (size_t)r * E_DIM + c);
    *(uint4*)&vs[r * HDIM + c] = *(const uint4*)(Vp + base + (size_t)r * E_DIM + c);
  }
  __syncthreads();
  const int d0 = (t >> 4) << 2, e0 = (t & 15) << 2;
  float acc[4][4] = {{0.f}};
  float z[4] = {0.f, 0.f, 0.f, 0.f};
  for (int c = 0; c < CHUNK_; ++c) {
    float kv4[4], vv4[4];
#pragma unroll
    for (int i = 0; i < 4; ++i) kv4[i] = b2f(ks[c * HDIM + d0 + i]);
#pragma unroll
    for (int j = 0; j < 4; ++j) vv4[j] = b2f(vs[c * HDIM + e0 + j]);
#pragma unroll
    for (int i = 0; i < 4; ++i) {
      z[i] += kv4[i];
#pragma unroll
      for (int j = 0; j < 4; ++j) acc[i][j] += kv4[i] * vv4[j];
    }
  }
  float* o = kvout + (size_t)bid * (HDIM * HDIM);
#pragma unroll
  for (int i = 0; i < 4; ++i)
#pragma unroll
    for (int j = 0; j < 4; ++j)
      o[(d0 + i) * HDIM + e0 + j] = acc[i][j];
  if (e0 == 0) {
#pragma unroll
    for (int i = 0; i < 4; ++i) zkout[(size_t)bid * HDIM + d0 + i] = z[i];
  }
}

// ---------------------------------------------------------------------------
// In-place exclusive prefix over chunks: S[n] <- sum_{m<n} S[m]; same for Z.
// One block per (b,h). Each thread owns fixed entries -> read-then-write safe.
// ---------------------------------------------------------------------------
__global__ __launch_bounds__(256)
void prefix_chunks(float* __restrict__ S, float* __restrict__ Z)
{
  const int bh = blockIdx.x;  // 0..63
  const int t = threadIdx.x;
  float run[16];
#pragma unroll
  for (int j = 0; j < 16; ++j) run[j] = 0.f;
  for (int n = 0; n < NCHUNK; ++n) {
    float* p = S + ((size_t)bh * NCHUNK + n) * (HDIM * HDIM);
#pragma unroll
    for (int j = 0; j < 16; ++j) {
      int idx = t + j * 256;
      float cur = p[idx];
      p[idx] = run[j];
      run[j] += cur;
    }
  }
  if (t < HDIM) {
    float rz = 0.f;
    for (int n = 0; n < NCHUNK; ++n) {
      float* p = Z + ((size_t)bh * NCHUNK + n) * HDIM + t;
      float cur = *p;
      *p = rz;
      rz += cur;
    }
  }
}

// ---------------------------------------------------------------------------
// Per-chunk output:
//   A[c,s] = <phiq[c], phik[s]> (s<=c);
//   num[c,e] = sum_s A[c,s] v[s,e] + sum_d phiq[c,d] S_prev[d,e]
//   den[c]   = sum_s A[c,s] + sum_d phiq[c,d] Z_prev[d] + eps
//   y = num/den
// One block per (b,h,n). Thread t: row c = t&127, col group g = t>>7 (32 cols).
// smax = c|63 is wave-uniform (lanes of a wave span a 64-aligned row block).
// ---------------------------------------------------------------------------
__global__ __launch_bounds__(256)
void chunk_attn(const __hip_bfloat16* __restrict__ Qp,
                const __hip_bfloat16* __restrict__ Kp,
                const __hip_bfloat16* __restrict__ Vp,
                const float* __restrict__ Sprev,
                const float* __restrict__ Zprev,
                __hip_bfloat16* __restrict__ Yp)
{
  const int bid = blockIdx.x;
  const int n = bid & 15, h = (bid >> 4) & 15, b = bid >> 8;
  __shared__ __align__(16) float ksf[CHUNK_ * HDIM];          // 32 KB (fp32: hot dot operand)
  __shared__ __align__(16) __hip_bfloat16 vs[CHUNK_ * HDIM];  // 16 KB
  __shared__ __align__(16) float Ss[HDIM * HDIM];             // 16 KB
  __shared__ float Zs[HDIM];
  const size_t base = ((size_t)(b * T_LEN + n * CHUNK_)) * E_DIM + h * HDIM;
  const int t = threadIdx.x;

  for (int i = t; i < CHUNK_ * 8; i += 256) {
    int r = i >> 3, c = (i & 7) << 3;
    uint4 kv_ = *(const uint4*)(Kp + base + (size_t)r * E_DIM + c);
    const __hip_bfloat16* kp8 = (const __hip_bfloat16*)&kv_;
#pragma unroll
    for (int j = 0; j < 8; ++j) ksf[r * HDIM + c + j] = b2f(kp8[j]);
    *(uint4*)&vs[r * HDIM + c] = *(const uint4*)(Vp + base + (size_t)r * E_DIM + c);
  }
  const float* Sg = Sprev + (size_t)bid * (HDIM * HDIM);
  for (int i = t; i < HDIM * HDIM; i += 256) Ss[i] = Sg[i];
  if (t < HDIM) Zs[t] = Zprev[(size_t)bid * HDIM + t];
  __syncthreads();

  const int g = t >> 7;   // column group (0/1), 32 cols each
  const int c = t & 127;  // row within chunk

  float qrow[HDIM];
  {
    const __hip_bfloat16* qp = Qp + base + (size_t)c * E_DIM;
#pragma unroll
    for (int d8 = 0; d8 < HDIM; d8 += 8) {
      uint4 u = *(const uint4*)(qp + d8);
      const __hip_bfloat16* q8 = (const __hip_bfloat16*)&u;
#pragma unroll
      for (int j = 0; j < 8; ++j) qrow[d8 + j] = b2f(q8[j]);
    }
  }

  float num[32];
#pragma unroll
  for (int e = 0; e < 32; ++e) num[e] = 0.f;
  float den = EPS_;

  // history part: phiq @ S_prev, phiq . Z_prev
#pragma unroll 4
  for (int d = 0; d < HDIM; ++d) {
    float qv = qrow[d];
    den += qv * Zs[d];
    const float* srow = &Ss[d * HDIM + g * 32];
#pragma unroll
    for (int e = 0; e < 32; ++e) num[e] += qv * srow[e];
  }

  // intra-chunk causal part
  const int smax = c | 63;  // wave-uniform trip count
  for (int s = 0; s <= smax; ++s) {
    const float* kr = &ksf[s * HDIM];
    float a = 0.f;
#pragma unroll
    for (int d = 0; d < HDIM; ++d) a += qrow[d] * kr[d];
    a = (s <= c) ? a : 0.f;
    den += a;
    const __hip_bfloat16* vr = &vs[s * HDIM + g * 32];
#pragma unroll
    for (int e = 0; e < 32; ++e) num[e] += a * b2f(vr[e]);
  }

  const float inv = 1.f / den;
  __hip_bfloat16* yp = Yp + base + (size_t)c * E_DIM + g * 32;
#pragma unroll
  for (int e = 0; e < 32; ++e) yp[e] = __float2bfloat16(num[e] * inv);
}

// ---------------------------------------------------------------------------
extern "C" void kernel_launch(void* const* d_in, const int* in_sizes, int n_in,
                              void* d_out, int out_size, void* d_ws, size_t ws_size,
                              hipStream_t stream)
{
  const float* x  = (const float*)d_in[0];
  const float* Wq = (const float*)d_in[1];
  const float* Wk = (const float*)d_in[2];
  const float* Wv = (const float*)d_in[3];
  const float* Wp = (const float*)d_in[4];
  const float* bp = (const float*)d_in[5];
  float* out = (float*)d_out;

  const size_t MT = (size_t)BATCH * T_LEN;  // 8192 rows
  char* w = (char*)d_ws;
  __hip_bfloat16* xb  = (__hip_bfloat16*)w; w += MT * E_DIM * sizeof(__hip_bfloat16);
  __hip_bfloat16* Wqb = (__hip_bfloat16*)w; w += (size_t)E_DIM * E_DIM * sizeof(__hip_bfloat16);
  __hip_bfloat16* Wkb = (__hip_bfloat16*)w; w += (size_t)E_DIM * E_DIM * sizeof(__hip_bfloat16);
  __hip_bfloat16* Wvb = (__hip_bfloat16*)w; w += (size_t)E_DIM * E_DIM * sizeof(__hip_bfloat16);
  __hip_bfloat16* Wpb = (__hip_bfloat16*)w; w += (size_t)E_DIM * E_DIM * sizeof(__hip_bfloat16);
  __hip_bfloat16* q = (__hip_bfloat16*)w; w += MT * E_DIM * sizeof(__hip_bfloat16);
  __hip_bfloat16* k = (__hip_bfloat16*)w; w += MT * E_DIM * sizeof(__hip_bfloat16);
  __hip_bfloat16* v = (__hip_bfloat16*)w; w += MT * E_DIM * sizeof(__hip_bfloat16);
  __hip_bfloat16* y = (__hip_bfloat16*)w; w += MT * E_DIM * sizeof(__hip_bfloat16);
  float* S = (float*)w; w += (size_t)BATCH * HEADS * NCHUNK * HDIM * HDIM * sizeof(float);
  float* Z = (float*)w; w += (size_t)BATCH * HEADS * NCHUNK * HDIM * sizeof(float);

  cast5<<<8192 + 4096, 256, 0, stream>>>(x, Wq, Wk, Wv, Wp, xb, Wqb, Wkb, Wvb, Wpb);

  dim3 grid(MT / 64, E_DIM / 64);  // (128, 16)
  gemm_nt<<<grid, 256, 0, stream>>>(xb, Wqb, nullptr, q, (int)MT, E_DIM, E_DIM, 1);
  gemm_nt<<<grid, 256, 0, stream>>>(xb, Wkb, nullptr, k, (int)MT, E_DIM, E_DIM, 1);
  gemm_nt<<<grid, 256, 0, stream>>>(xb, Wvb, nullptr, v, (int)MT, E_DIM, E_DIM, 0);
  chunk_kv<<<BATCH * HEADS * NCHUNK, 256, 0, stream>>>(k, v, S, Z);
  prefix_chunks<<<BATCH * HEADS, 256, 0, stream>>>(S, Z);
  chunk_attn<<<BATCH * HEADS * NCHUNK, 256, 0, stream>>>(q, k, v, S, Z, y);
  gemm_nt<<<grid, 256, 0, stream>>>(y, Wpb, bp, out, (int)MT, E_DIM, E_DIM, 2);
}

// Round 3
// 256.249 us; speedup vs baseline: 1.7668x; 1.7668x over previous
//
#include <hip/hip_runtime.h>
#include <hip/hip_bf16.h>
#include <stdint.h>

#define T_LEN  2048
#define E_DIM  1024
#define BATCH  4
#define HEADS  16
#define HDIM   64
#define CHUNK_ 128
#define NCHUNK 16
#define EPS_   1e-6f

typedef __attribute__((ext_vector_type(8))) short bf16x8;
typedef __attribute__((ext_vector_type(4))) float f32x4;

__device__ __forceinline__ float b2f(__hip_bfloat16 h) { return __bfloat162float(h); }
__device__ __forceinline__ unsigned short f2bu(float f) {
  __hip_bfloat16 h = __float2bfloat16(f);
  return *(unsigned short*)&h;
}
__device__ __forceinline__ float bs2f(short v) {
  union { unsigned int u; float f; } c;
  c.u = ((unsigned int)(unsigned short)v) << 16;
  return c.f;
}
// async global->LDS, 16B per lane; LDS dest = base + lane*16 (wave-uniform base)
__device__ __forceinline__ void gld_lds16(const void* g, void* l) {
  __builtin_amdgcn_global_load_lds((const __attribute__((address_space(1))) void*)g,
                                   (__attribute__((address_space(3))) void*)l,
                                   16, 0, 0);
}

// ---------------------------------------------------------------------------
// fp32 -> bf16 cast for x (8192x1024) and four 1024x1024 weights.
// ---------------------------------------------------------------------------
__global__ __launch_bounds__(256)
void cast5(const float* __restrict__ x,  const float* __restrict__ w0,
           const float* __restrict__ w1, const float* __restrict__ w2,
           const float* __restrict__ w3,
           __hip_bfloat16* __restrict__ xb,  __hip_bfloat16* __restrict__ w0b,
           __hip_bfloat16* __restrict__ w1b, __hip_bfloat16* __restrict__ w2b,
           __hip_bfloat16* __restrict__ w3b)
{
  const int b = blockIdx.x;
  const float* s;
  __hip_bfloat16* d;
  size_t off;
  if (b < 8192) { s = x; d = xb; off = (size_t)b * 1024; }
  else {
    const int i = (b - 8192) >> 10;
    const int r = (b - 8192) & 1023;
    s = (i == 0) ? w0 : (i == 1) ? w1 : (i == 2) ? w2 : w3;
    d = (i == 0) ? w0b : (i == 1) ? w1b : (i == 2) ? w2b : w3b;
    off = (size_t)r * 1024;
  }
  const int t = threadIdx.x;
  float4 v = *(const float4*)(s + off + (size_t)t * 4);
  ushort4 o;
  o.x = f2bu(v.x); o.y = f2bu(v.y); o.z = f2bu(v.z); o.w = f2bu(v.w);
  *(ushort4*)((unsigned short*)d + off + (size_t)t * 4) = o;
}

// ---------------------------------------------------------------------------
// 128x128 GEMM core (m97 structure): BK=32, global_load_lds width=16,
// LDS row-major [m][32k] (64B rows), wave w owns 64x64 quadrant.
// C[m,n] = sum_k X[m,k]*W[n,k]; M=8192-ish rows via bm, K=N=1024.
// ---------------------------------------------------------------------------
__device__ __forceinline__ void gemm128_core(
    const __hip_bfloat16* __restrict__ X,
    const __hip_bfloat16* __restrict__ W,
    int bm, int bn, f32x4 acc[4][4],
    __hip_bfloat16* Xs, __hip_bfloat16* Ws)
{
  const int t = threadIdx.x, lane = t & 63, wave = t >> 6;
  const int wm = (wave >> 1) * 64, wn = (wave & 1) * 64;
  for (int k0 = 0; k0 < 1024; k0 += 32) {
    if (k0) __syncthreads();
#pragma unroll
    for (int i = 0; i < 2; ++i) {
      const int j = wave * 2 + i;
      const int m = j * 16 + (lane >> 2);
      const int kg = lane & 3;
      gld_lds16(X + (size_t)(bm * 128 + m) * 1024 + k0 + kg * 8, (char*)Xs + j * 1024);
      gld_lds16(W + (size_t)(bn * 128 + m) * 1024 + k0 + kg * 8, (char*)Ws + j * 1024);
    }
    __syncthreads();
    bf16x8 a[4], b[4];
#pragma unroll
    for (int i = 0; i < 4; ++i) {
      a[i] = *(const bf16x8*)&Xs[((wm + i * 16 + (lane & 15)) * 4 + (lane >> 4)) * 8];
      b[i] = *(const bf16x8*)&Ws[((wn + i * 16 + (lane & 15)) * 4 + (lane >> 4)) * 8];
    }
#pragma unroll
    for (int i = 0; i < 4; ++i)
#pragma unroll
      for (int jn = 0; jn < 4; ++jn)
        acc[i][jn] = __builtin_amdgcn_mfma_f32_16x16x32_bf16(a[i], b[jn], acc[i][jn], 0, 0, 0);
  }
}

// fused q/k/v projection: grid (64, 24); bn>>3 selects {q,k,v}
__global__ __launch_bounds__(256, 2)
void gemm_qkv(const __hip_bfloat16* __restrict__ X,
              const __hip_bfloat16* __restrict__ Wq,
              const __hip_bfloat16* __restrict__ Wk,
              const __hip_bfloat16* __restrict__ Wv,
              __hip_bfloat16* __restrict__ qo,
              __hip_bfloat16* __restrict__ ko,
              __hip_bfloat16* __restrict__ vo)
{
  __shared__ __align__(16) __hip_bfloat16 Xs[128 * 32];
  __shared__ __align__(16) __hip_bfloat16 Ws[128 * 32];
  const int bm = blockIdx.x, bnx = blockIdx.y;
  const int which = bnx >> 3, bn = bnx & 7;
  const __hip_bfloat16* W = (which == 0) ? Wq : (which == 1) ? Wk : Wv;
  __hip_bfloat16* C = (which == 0) ? qo : (which == 1) ? ko : vo;
  const bool elu = (which < 2);
  f32x4 acc[4][4];
#pragma unroll
  for (int i = 0; i < 4; ++i)
#pragma unroll
    for (int j = 0; j < 4; ++j) acc[i][j] = (f32x4){0.f, 0.f, 0.f, 0.f};
  gemm128_core(X, W, bm, bn, acc, Xs, Ws);
  const int lane = threadIdx.x & 63, wave = threadIdx.x >> 6;
  const int wm = (wave >> 1) * 64, wn = (wave & 1) * 64;
  const int r0 = (lane >> 4) * 4;
#pragma unroll
  for (int mi = 0; mi < 4; ++mi)
#pragma unroll
    for (int ni = 0; ni < 4; ++ni) {
      const int row = bm * 128 + wm + mi * 16 + r0;
      const int col = bn * 128 + wn + ni * 16 + (lane & 15);
#pragma unroll
      for (int r = 0; r < 4; ++r) {
        float v = acc[mi][ni][r];
        if (elu) v = (v > 0.f) ? (v + 1.f) : __expf(v);
        C[(size_t)(row + r) * 1024 + col] = __float2bfloat16(v);
      }
    }
}

// output projection: fp32 out + bias; grid (64, 8)
__global__ __launch_bounds__(256, 2)
void gemm_out(const __hip_bfloat16* __restrict__ X,
              const __hip_bfloat16* __restrict__ W,
              const float* __restrict__ bias,
              float* __restrict__ C)
{
  __shared__ __align__(16) __hip_bfloat16 Xs[128 * 32];
  __shared__ __align__(16) __hip_bfloat16 Ws[128 * 32];
  const int bm = blockIdx.x, bn = blockIdx.y;
  f32x4 acc[4][4];
#pragma unroll
  for (int i = 0; i < 4; ++i)
#pragma unroll
    for (int j = 0; j < 4; ++j) acc[i][j] = (f32x4){0.f, 0.f, 0.f, 0.f};
  gemm128_core(X, W, bm, bn, acc, Xs, Ws);
  const int lane = threadIdx.x & 63, wave = threadIdx.x >> 6;
  const int wm = (wave >> 1) * 64, wn = (wave & 1) * 64;
  const int r0 = (lane >> 4) * 4;
#pragma unroll
  for (int mi = 0; mi < 4; ++mi)
#pragma unroll
    for (int ni = 0; ni < 4; ++ni) {
      const int row = bm * 128 + wm + mi * 16 + r0;
      const int col = bn * 128 + wn + ni * 16 + (lane & 15);
      const float bv = bias[col];
#pragma unroll
      for (int r = 0; r < 4; ++r)
        C[(size_t)(row + r) * 1024 + col] = acc[mi][ni][r] + bv;
    }
}

// ---------------------------------------------------------------------------
// Per-chunk KV state, stored TRANSPOSED: S_T[e][d] = sum_c phik[c,d]*v[c,e].
// ---------------------------------------------------------------------------
__global__ __launch_bounds__(256)
void chunk_kv(const __hip_bfloat16* __restrict__ Kp,
              const __hip_bfloat16* __restrict__ Vp,
              float* __restrict__ kvout, float* __restrict__ zkout)
{
  const int bid = blockIdx.x;  // b*256 + h*16 + n
  const int n = bid & 15, h = (bid >> 4) & 15, b = bid >> 8;
  __shared__ __align__(16) __hip_bfloat16 ks[CHUNK_ * HDIM];
  __shared__ __align__(16) __hip_bfloat16 vs[CHUNK_ * HDIM];
  const size_t base = ((size_t)(b * T_LEN + n * CHUNK_)) * E_DIM + h * HDIM;
  const int t = threadIdx.x;
  for (int i = t; i < CHUNK_ * 8; i += 256) {
    int r = i >> 3, c = (i & 7) << 3;
    *(uint4*)&ks[r * HDIM + c] = *(const uint4*)(Kp + base + (size_t)r * E_DIM + c);
    *(uint4*)&vs[r * HDIM + c] = *(const uint4*)(Vp + base + (size_t)r * E_DIM + c);
  }
  __syncthreads();
  const int d0 = (t >> 4) << 2, e0 = (t & 15) << 2;
  float acc[4][4] = {{0.f}};
  float z[4] = {0.f, 0.f, 0.f, 0.f};
  for (int c = 0; c < CHUNK_; ++c) {
    float kv4[4], vv4[4];
#pragma unroll
    for (int i = 0; i < 4; ++i) kv4[i] = b2f(ks[c * HDIM + d0 + i]);
#pragma unroll
    for (int j = 0; j < 4; ++j) vv4[j] = b2f(vs[c * HDIM + e0 + j]);
#pragma unroll
    for (int i = 0; i < 4; ++i) {
      z[i] += kv4[i];
#pragma unroll
      for (int j = 0; j < 4; ++j) acc[i][j] += kv4[i] * vv4[j];
    }
  }
  float* o = kvout + (size_t)bid * (HDIM * HDIM);
#pragma unroll
  for (int i = 0; i < 4; ++i)
#pragma unroll
    for (int j = 0; j < 4; ++j)
      o[(e0 + j) * HDIM + (d0 + i)] = acc[i][j];  // TRANSPOSED store
  if (e0 == 0) {
#pragma unroll
    for (int i = 0; i < 4; ++i) zkout[(size_t)bid * HDIM + d0 + i] = z[i];
  }
}

// ---------------------------------------------------------------------------
// In-place exclusive prefix over chunks (elementwise on flat tiles).
// ---------------------------------------------------------------------------
__global__ __launch_bounds__(256)
void prefix_chunks(float* __restrict__ S, float* __restrict__ Z)
{
  const int bh = blockIdx.x;
  const int t = threadIdx.x;
  float run[16];
#pragma unroll
  for (int j = 0; j < 16; ++j) run[j] = 0.f;
  for (int n = 0; n < NCHUNK; ++n) {
    float* p = S + ((size_t)bh * NCHUNK + n) * (HDIM * HDIM);
#pragma unroll
    for (int j = 0; j < 16; ++j) {
      int idx = t + j * 256;
      float cur = p[idx];
      p[idx] = run[j];
      run[j] += cur;
    }
  }
  if (t < HDIM) {
    float rz = 0.f;
    for (int n = 0; n < NCHUNK; ++n) {
      float* p = Z + ((size_t)bh * NCHUNK + n) * HDIM + t;
      float cur = *p;
      *p = rz;
      rz += cur;
    }
  }
}

// ---------------------------------------------------------------------------
// MFMA chunk_attn. One block per (b,h,n), 4 waves.
// LDS: QK = phiq [kg0..7][m] (16KB) + phik [kg0..7][s] (16KB), later reused
// as P [kgs0..15][m] (32KB). Vt = v natural [s][e]. Sb = S_prev as B-operand
// [kgd][e] (elem j = S_prev[kg*8+j][e]).
// Wave w owns m-tiles {w, 7-w} (balanced causal work).
// ---------------------------------------------------------------------------
__global__ __launch_bounds__(256, 2)
void chunk_attn(const __hip_bfloat16* __restrict__ Qp,
                const __hip_bfloat16* __restrict__ Kp,
                const __hip_bfloat16* __restrict__ Vp,
                const float* __restrict__ STp,   // [bid][e][d] fp32
                const float* __restrict__ Zp,    // [bid][d]
                __hip_bfloat16* __restrict__ Yp)
{
  __shared__ __align__(16) __hip_bfloat16 QK[16384];  // 32 KB
  __shared__ __align__(16) __hip_bfloat16 Vt[8192];   // 16 KB
  __shared__ __align__(16) __hip_bfloat16 Sb[4096];   // 8 KB
  __shared__ float den_lds[128];
  __shared__ float Zs[64];

  const int bid = blockIdx.x;
  const int n = bid & 15, h = (bid >> 4) & 15, b = bid >> 8;
  const int tokbase = b * T_LEN + n * CHUNK_;
  const size_t gbase = (size_t)tokbase * E_DIM + h * HDIM;
  const int t = threadIdx.x, lane = t & 63, wv = t >> 6;
  unsigned short* QKu = (unsigned short*)QK;
  short* VtS = (short*)Vt;

  // ---- stage phiq, phik: coalesced global read, [kg][m] LDS slots ----
#pragma unroll
  for (int i = 0; i < 4; ++i) {
    const int m = i * 32 + (t >> 3);
    const int d0 = (t & 7) << 3;
    uint4 qv = *(const uint4*)(Qp + gbase + (size_t)m * E_DIM + d0);
    uint4 kv = *(const uint4*)(Kp + gbase + (size_t)m * E_DIM + d0);
    *(uint4*)&QK[((d0 >> 3) * 128 + m) * 8] = qv;
    *(uint4*)&QK[8192 + ((d0 >> 3) * 128 + m) * 8] = kv;
  }
  // ---- stage v natural [s][e] via global_load_lds ----
#pragma unroll
  for (int i = 0; i < 4; ++i) {
    const int j = wv * 4 + i;
    const int slot = j * 64 + lane;
    const int s = slot >> 3, e8 = slot & 7;
    gld_lds16(Vp + gbase + (size_t)s * E_DIM + e8 * 8, (char*)Vt + j * 1024);
  }
  // ---- stage S_prev (fp32 -> bf16) into B-operand layout [kgd][e] ----
  {
    const float* Sg = STp + (size_t)bid * (HDIM * HDIM);
    const int e = t >> 2, quad = t & 3;
#pragma unroll
    for (int i = 0; i < 4; ++i) {
      const int d0 = quad * 16 + i * 4;
      float4 sv = *(const float4*)(Sg + e * HDIM + d0);
      ushort4 o;
      o.x = f2bu(sv.x); o.y = f2bu(sv.y); o.z = f2bu(sv.z); o.w = f2bu(sv.w);
      *(ushort4*)&QKu[0] ;  // (no-op guard removed below)
      *(ushort4*)&((unsigned short*)Sb)[((d0 >> 3) * 64 + e) * 8 + (d0 & 7)] = o;
    }
  }
  if (t < 64) Zs[t] = Zp[(size_t)bid * HDIM + t];
  __syncthreads();  // B1: all staging visible (drains global_load_lds too)

  const int mts[2] = { wv, 7 - wv };
  f32x4 accn[2][4];
#pragma unroll
  for (int i = 0; i < 2; ++i)
#pragma unroll
    for (int j = 0; j < 4; ++j) accn[i][j] = (f32x4){0.f, 0.f, 0.f, 0.f};

  // ---- phase A: history num (phiq @ S_prev), den-init, step-1 (A = phiq phik^T)
  // step 4: num += phiq @ S_prev
#pragma unroll
  for (int mi = 0; mi < 2; ++mi) {
    const int m0 = mts[mi] * 16;
#pragma unroll
    for (int kh = 0; kh < 2; ++kh) {
      bf16x8 a = *(const bf16x8*)&QK[(((kh * 4) + (lane >> 4)) * 128 + m0 + (lane & 15)) * 8];
#pragma unroll
      for (int ne = 0; ne < 4; ++ne) {
        bf16x8 bsf = *(const bf16x8*)&Sb[(((kh * 4) + (lane >> 4)) * 64 + ne * 16 + (lane & 15)) * 8];
        accn[mi][ne] = __builtin_amdgcn_mfma_f32_16x16x32_bf16(a, bsf, accn[mi][ne], 0, 0, 0);
      }
    }
  }
  // den-init: EPS + phiq . Z_prev  (rows 0..127 by t<128)
  if (t < 128) {
    float dn = EPS_;
#pragma unroll
    for (int kg = 0; kg < 8; ++kg) {
      bf16x8 qv = *(const bf16x8*)&QK[(kg * 128 + t) * 8];
#pragma unroll
      for (int j = 0; j < 8; ++j) dn += bs2f(qv[j]) * Zs[kg * 8 + j];
    }
    den_lds[t] = dn;
  }
  // step 1: A = phiq @ phik^T (causal), packed bf16 held in regs
  uint2 packP[9];
  {
    int np = 0;
#pragma unroll
    for (int mi = 0; mi < 2; ++mi) {
      const int mt = mts[mi], m0 = mt * 16;
      bf16x8 aq0 = *(const bf16x8*)&QK[(((lane >> 4)) * 128 + m0 + (lane & 15)) * 8];
      bf16x8 aq1 = *(const bf16x8*)&QK[((4 + (lane >> 4)) * 128 + m0 + (lane & 15)) * 8];
      for (int nt = 0; nt <= mt; ++nt) {
        f32x4 acc = (f32x4){0.f, 0.f, 0.f, 0.f};
        bf16x8 b0 = *(const bf16x8*)&QK[8192 + (((lane >> 4)) * 128 + nt * 16 + (lane & 15)) * 8];
        bf16x8 b1 = *(const bf16x8*)&QK[8192 + ((4 + (lane >> 4)) * 128 + nt * 16 + (lane & 15)) * 8];
        acc = __builtin_amdgcn_mfma_f32_16x16x32_bf16(aq0, b0, acc, 0, 0, 0);
        acc = __builtin_amdgcn_mfma_f32_16x16x32_bf16(aq1, b1, acc, 0, 0, 0);
        unsigned short u[4];
#pragma unroll
        for (int r = 0; r < 4; ++r) {
          float v = acc[r];
          if (nt == mt) {  // diagonal tile: keep iff s<=m
            const bool keep = (lane & 15) <= (((lane >> 4) * 4) + r);
            v = keep ? v : 0.f;
          }
          u[r] = f2bu(v);
        }
        packP[np].x = (unsigned)u[0] | ((unsigned)u[1] << 16);
        packP[np].y = (unsigned)u[2] | ((unsigned)u[3] << 16);
        ++np;
      }
    }
  }
  __syncthreads();  // B2: all reads of phiq/phik done -> safe to overwrite with P

  // ---- write P into QK region, layout [kgs 0..15][m], elem = s&7 ----
  {
    int np = 0;
#pragma unroll
    for (int mi = 0; mi < 2; ++mi) {
      const int mt = mts[mi], m0 = mt * 16;
      for (int nt = 0; nt <= mt; ++nt) {
        const uint2 p = packP[np++];
        const int s = nt * 16 + (lane & 15);
        const int kgs = s >> 3, se = s & 7;
#pragma unroll
        for (int r = 0; r < 4; ++r) {
          const int m = m0 + (lane >> 4) * 4 + r;
          unsigned short us = (r < 2) ? (unsigned short)(p.x >> (r * 16))
                                      : (unsigned short)(p.y >> ((r - 2) * 16));
          QKu[(kgs * 128 + m) * 8 + se] = us;
        }
      }
      // zero-fill unwritten strip for even m-tiles (kgs = 2mt+2, 2mt+3)
      if ((mt & 1) == 0 && lane < 32) {
        const int slot = (2 * mt + 2 + (lane >> 4)) * 128 + m0 + (lane & 15);
        *(uint4*)&QK[slot * 8] = (uint4){0u, 0u, 0u, 0u};
      }
    }
  }
  __syncthreads();  // B3: P visible

  // ---- step 3: num += P @ v ; den += rowsum(P) via ones-B ----
  bf16x8 ones;
#pragma unroll
  for (int j = 0; j < 8; ++j) ones[j] = (short)0x3F80;
  f32x4 accden[2];
  accden[0] = (f32x4){0.f, 0.f, 0.f, 0.f};
  accden[1] = (f32x4){0.f, 0.f, 0.f, 0.f};
#pragma unroll
  for (int mi = 0; mi < 2; ++mi) {
    const int mt = mts[mi], m0 = mt * 16;
    const int ktc = (mt + 2) >> 1;
    for (int kt = 0; kt < ktc; ++kt) {
      bf16x8 a = *(const bf16x8*)&QK[((kt * 4 + (lane >> 4)) * 128 + m0 + (lane & 15)) * 8];
      accden[mi] = __builtin_amdgcn_mfma_f32_16x16x32_bf16(a, ones, accden[mi], 0, 0, 0);
#pragma unroll
      for (int ne = 0; ne < 4; ++ne) {
        bf16x8 bv;
#pragma unroll
        for (int j = 0; j < 8; ++j)
          bv[j] = VtS[(kt * 32 + (lane >> 4) * 8 + j) * 64 + ne * 16 + (lane & 15)];
        accn[mi][ne] = __builtin_amdgcn_mfma_f32_16x16x32_bf16(a, bv, accn[mi][ne], 0, 0, 0);
      }
    }
    if ((lane & 15) == 0) {
#pragma unroll
      for (int r = 0; r < 4; ++r)
        den_lds[m0 + (lane >> 4) * 4 + r] += accden[mi][r];
    }
  }
  __syncthreads();  // B4: den final

  // ---- epilogue: y = num / den ----
#pragma unroll
  for (int mi = 0; mi < 2; ++mi) {
    const int m0 = mts[mi] * 16;
    float inv[4];
#pragma unroll
    for (int r = 0; r < 4; ++r)
      inv[r] = 1.f / den_lds[m0 + (lane >> 4) * 4 + r];
#pragma unroll
    for (int ne = 0; ne < 4; ++ne) {
      const int col = h * HDIM + ne * 16 + (lane & 15);
#pragma unroll
      for (int r = 0; r < 4; ++r) {
        const int row = tokbase + m0 + (lane >> 4) * 4 + r;
        Yp[(size_t)row * E_DIM + col] = __float2bfloat16(accn[mi][ne][r] * inv[r]);
      }
    }
  }
}

// ---------------------------------------------------------------------------
extern "C" void kernel_launch(void* const* d_in, const int* in_sizes, int n_in,
                              void* d_out, int out_size, void* d_ws, size_t ws_size,
                              hipStream_t stream)
{
  const float* x  = (const float*)d_in[0];
  const float* Wq = (const float*)d_in[1];
  const float* Wk = (const float*)d_in[2];
  const float* Wv = (const float*)d_in[3];
  const float* Wp = (const float*)d_in[4];
  const float* bp = (const float*)d_in[5];
  float* out = (float*)d_out;

  const size_t MT = (size_t)BATCH * T_LEN;  // 8192 rows
  char* w = (char*)d_ws;
  __hip_bfloat16* xb  = (__hip_bfloat16*)w; w += MT * E_DIM * sizeof(__hip_bfloat16);
  __hip_bfloat16* Wqb = (__hip_bfloat16*)w; w += (size_t)E_DIM * E_DIM * sizeof(__hip_bfloat16);
  __hip_bfloat16* Wkb = (__hip_bfloat16*)w; w += (size_t)E_DIM * E_DIM * sizeof(__hip_bfloat16);
  __hip_bfloat16* Wvb = (__hip_bfloat16*)w; w += (size_t)E_DIM * E_DIM * sizeof(__hip_bfloat16);
  __hip_bfloat16* Wpb = (__hip_bfloat16*)w; w += (size_t)E_DIM * E_DIM * sizeof(__hip_bfloat16);
  __hip_bfloat16* q = (__hip_bfloat16*)w; w += MT * E_DIM * sizeof(__hip_bfloat16);
  __hip_bfloat16* k = (__hip_bfloat16*)w; w += MT * E_DIM * sizeof(__hip_bfloat16);
  __hip_bfloat16* v = (__hip_bfloat16*)w; w += MT * E_DIM * sizeof(__hip_bfloat16);
  __hip_bfloat16* y = (__hip_bfloat16*)w; w += MT * E_DIM * sizeof(__hip_bfloat16);
  float* S = (float*)w; w += (size_t)BATCH * HEADS * NCHUNK * HDIM * HDIM * sizeof(float);
  float* Z = (float*)w; w += (size_t)BATCH * HEADS * NCHUNK * HDIM * sizeof(float);

  cast5<<<8192 + 4096, 256, 0, stream>>>(x, Wq, Wk, Wv, Wp, xb, Wqb, Wkb, Wvb, Wpb);
  gemm_qkv<<<dim3(MT / 128, 24), 256, 0, stream>>>(xb, Wqb, Wkb, Wvb, q, k, v);
  chunk_kv<<<BATCH * HEADS * NCHUNK, 256, 0, stream>>>(k, v, S, Z);
  prefix_chunks<<<BATCH * HEADS, 256, 0, stream>>>(S, Z);
  chunk_attn<<<BATCH * HEADS * NCHUNK, 256, 0, stream>>>(q, k, v, S, Z, y);
  gemm_out<<<dim3(MT / 128, 8), 256, 0, stream>>>(y, Wpb, bp, out);
}

// Round 4
// 247.666 us; speedup vs baseline: 1.8280x; 1.0347x over previous
//
#include <hip/hip_runtime.h>
#include <hip/hip_bf16.h>
#include <stdint.h>

#define T_LEN  2048
#define E_DIM  1024
#define BATCH  4
#define HEADS  16
#define HDIM   64
#define CHUNK_ 128
#define NCHUNK 16
#define EPS_   1e-6f

typedef __attribute__((ext_vector_type(8))) short bf16x8;
typedef __attribute__((ext_vector_type(4))) float f32x4;

__device__ __forceinline__ float b2f(__hip_bfloat16 h) { return __bfloat162float(h); }
__device__ __forceinline__ unsigned short f2bu(float f) {
  __hip_bfloat16 h = __float2bfloat16(f);
  return *(unsigned short*)&h;
}
// async global->LDS, 16B per lane; LDS dest = base + lane*16 (wave-uniform base)
__device__ __forceinline__ void gld_lds16(const void* g, void* l) {
  __builtin_amdgcn_global_load_lds((const __attribute__((address_space(1))) void*)g,
                                   (__attribute__((address_space(3))) void*)l,
                                   16, 0, 0);
}

// ---------------------------------------------------------------------------
// fp32 -> bf16 cast for x (8192x1024) and four 1024x1024 weights.
// ---------------------------------------------------------------------------
__global__ __launch_bounds__(256)
void cast5(const float* __restrict__ x,  const float* __restrict__ w0,
           const float* __restrict__ w1, const float* __restrict__ w2,
           const float* __restrict__ w3,
           __hip_bfloat16* __restrict__ xb,  __hip_bfloat16* __restrict__ w0b,
           __hip_bfloat16* __restrict__ w1b, __hip_bfloat16* __restrict__ w2b,
           __hip_bfloat16* __restrict__ w3b)
{
  const int b = blockIdx.x;
  const float* s;
  __hip_bfloat16* d;
  size_t off;
  if (b < 8192) { s = x; d = xb; off = (size_t)b * 1024; }
  else {
    const int i = (b - 8192) >> 10;
    const int r = (b - 8192) & 1023;
    s = (i == 0) ? w0 : (i == 1) ? w1 : (i == 2) ? w2 : w3;
    d = (i == 0) ? w0b : (i == 1) ? w1b : (i == 2) ? w2b : w3b;
    off = (size_t)r * 1024;
  }
  const int t = threadIdx.x;
  float4 v = *(const float4*)(s + off + (size_t)t * 4);
  ushort4 o;
  o.x = f2bu(v.x); o.y = f2bu(v.y); o.z = f2bu(v.z); o.w = f2bu(v.w);
  *(ushort4*)((unsigned short*)d + off + (size_t)t * 4) = o;
}

// ---------------------------------------------------------------------------
// 128x128 GEMM core (m97 structure): BK=32, global_load_lds width=16,
// LDS row-major [m][32k] (64B rows), wave w owns 64x64 quadrant.
// ---------------------------------------------------------------------------
__device__ __forceinline__ void gemm128_core(
    const __hip_bfloat16* __restrict__ X,
    const __hip_bfloat16* __restrict__ W,
    int bm, int bn, f32x4 acc[4][4],
    __hip_bfloat16* Xs, __hip_bfloat16* Ws)
{
  const int t = threadIdx.x, lane = t & 63, wave = t >> 6;
  const int wm = (wave >> 1) * 64, wn = (wave & 1) * 64;
  for (int k0 = 0; k0 < 1024; k0 += 32) {
    if (k0) __syncthreads();
#pragma unroll
    for (int i = 0; i < 2; ++i) {
      const int j = wave * 2 + i;
      const int m = j * 16 + (lane >> 2);
      const int kg = lane & 3;
      gld_lds16(X + (size_t)(bm * 128 + m) * 1024 + k0 + kg * 8, (char*)Xs + j * 1024);
      gld_lds16(W + (size_t)(bn * 128 + m) * 1024 + k0 + kg * 8, (char*)Ws + j * 1024);
    }
    __syncthreads();
    bf16x8 a[4], b[4];
#pragma unroll
    for (int i = 0; i < 4; ++i) {
      a[i] = *(const bf16x8*)&Xs[((wm + i * 16 + (lane & 15)) * 4 + (lane >> 4)) * 8];
      b[i] = *(const bf16x8*)&Ws[((wn + i * 16 + (lane & 15)) * 4 + (lane >> 4)) * 8];
    }
#pragma unroll
    for (int i = 0; i < 4; ++i)
#pragma unroll
      for (int jn = 0; jn < 4; ++jn)
        acc[i][jn] = __builtin_amdgcn_mfma_f32_16x16x32_bf16(a[i], b[jn], acc[i][jn], 0, 0, 0);
  }
}

// fused q/k/v projection: grid (64, 24); bn>>3 selects {q,k,v}
__global__ __launch_bounds__(256, 2)
void gemm_qkv(const __hip_bfloat16* __restrict__ X,
              const __hip_bfloat16* __restrict__ Wq,
              const __hip_bfloat16* __restrict__ Wk,
              const __hip_bfloat16* __restrict__ Wv,
              __hip_bfloat16* __restrict__ qo,
              __hip_bfloat16* __restrict__ ko,
              __hip_bfloat16* __restrict__ vo)
{
  __shared__ __align__(16) __hip_bfloat16 Xs[128 * 32];
  __shared__ __align__(16) __hip_bfloat16 Ws[128 * 32];
  const int bm = blockIdx.x, bnx = blockIdx.y;
  const int which = bnx >> 3, bn = bnx & 7;
  const __hip_bfloat16* W = (which == 0) ? Wq : (which == 1) ? Wk : Wv;
  __hip_bfloat16* C = (which == 0) ? qo : (which == 1) ? ko : vo;
  const bool elu = (which < 2);
  f32x4 acc[4][4];
#pragma unroll
  for (int i = 0; i < 4; ++i)
#pragma unroll
    for (int j = 0; j < 4; ++j) acc[i][j] = (f32x4){0.f, 0.f, 0.f, 0.f};
  gemm128_core(X, W, bm, bn, acc, Xs, Ws);
  const int lane = threadIdx.x & 63, wave = threadIdx.x >> 6;
  const int wm = (wave >> 1) * 64, wn = (wave & 1) * 64;
  const int r0 = (lane >> 4) * 4;
#pragma unroll
  for (int mi = 0; mi < 4; ++mi)
#pragma unroll
    for (int ni = 0; ni < 4; ++ni) {
      const int row = bm * 128 + wm + mi * 16 + r0;
      const int col = bn * 128 + wn + ni * 16 + (lane & 15);
#pragma unroll
      for (int r = 0; r < 4; ++r) {
        float v = acc[mi][ni][r];
        if (elu) v = (v > 0.f) ? (v + 1.f) : __expf(v);
        C[(size_t)(row + r) * 1024 + col] = __float2bfloat16(v);
      }
    }
}

// output projection: fp32 out + bias; grid (64, 8)
__global__ __launch_bounds__(256, 2)
void gemm_out(const __hip_bfloat16* __restrict__ X,
              const __hip_bfloat16* __restrict__ W,
              const float* __restrict__ bias,
              float* __restrict__ C)
{
  __shared__ __align__(16) __hip_bfloat16 Xs[128 * 32];
  __shared__ __align__(16) __hip_bfloat16 Ws[128 * 32];
  const int bm = blockIdx.x, bn = blockIdx.y;
  f32x4 acc[4][4];
#pragma unroll
  for (int i = 0; i < 4; ++i)
#pragma unroll
    for (int j = 0; j < 4; ++j) acc[i][j] = (f32x4){0.f, 0.f, 0.f, 0.f};
  gemm128_core(X, W, bm, bn, acc, Xs, Ws);
  const int lane = threadIdx.x & 63, wave = threadIdx.x >> 6;
  const int wm = (wave >> 1) * 64, wn = (wave & 1) * 64;
  const int r0 = (lane >> 4) * 4;
#pragma unroll
  for (int mi = 0; mi < 4; ++mi)
#pragma unroll
    for (int ni = 0; ni < 4; ++ni) {
      const int row = bm * 128 + wm + mi * 16 + r0;
      const int col = bn * 128 + wn + ni * 16 + (lane & 15);
      const float bv = bias[col];
#pragma unroll
      for (int r = 0; r < 4; ++r)
        C[(size_t)(row + r) * 1024 + col] = acc[mi][ni][r] + bv;
    }
}

// ---------------------------------------------------------------------------
// Per-chunk KV state in B-frag IMAGE layout:
//   Simg flat idx = (d>>3)*512 + e*8 + (d&7)  (fp32, prefix-summed later)
// Also emits V image: vimg[bid][sg*64+e][j] = v[sg*8+j][e] (bf16).
// ---------------------------------------------------------------------------
__global__ __launch_bounds__(256)
void chunk_kv(const __hip_bfloat16* __restrict__ Kp,
              const __hip_bfloat16* __restrict__ Vp,
              float* __restrict__ kvout, float* __restrict__ zkout,
              unsigned short* __restrict__ vimg)
{
  const int bid = blockIdx.x;  // b*256 + h*16 + n
  const int n = bid & 15, h = (bid >> 4) & 15, b = bid >> 8;
  __shared__ __align__(16) __hip_bfloat16 ks[CHUNK_ * HDIM];
  __shared__ __align__(16) __hip_bfloat16 vs[CHUNK_ * HDIM];
  const size_t base = ((size_t)(b * T_LEN + n * CHUNK_)) * E_DIM + h * HDIM;
  const int t = threadIdx.x;
  for (int i = t; i < CHUNK_ * 8; i += 256) {
    int r = i >> 3, c = (i & 7) << 3;
    *(uint4*)&ks[r * HDIM + c] = *(const uint4*)(Kp + base + (size_t)r * E_DIM + c);
    *(uint4*)&vs[r * HDIM + c] = *(const uint4*)(Vp + base + (size_t)r * E_DIM + c);
  }
  __syncthreads();
  const int d0 = (t >> 4) << 2, e0 = (t & 15) << 2;
  float acc[4][4] = {{0.f}};
  float z[4] = {0.f, 0.f, 0.f, 0.f};
  for (int c = 0; c < CHUNK_; ++c) {
    float kv4[4], vv4[4];
#pragma unroll
    for (int i = 0; i < 4; ++i) kv4[i] = b2f(ks[c * HDIM + d0 + i]);
#pragma unroll
    for (int j = 0; j < 4; ++j) vv4[j] = b2f(vs[c * HDIM + e0 + j]);
#pragma unroll
    for (int i = 0; i < 4; ++i) {
      z[i] += kv4[i];
#pragma unroll
      for (int j = 0; j < 4; ++j) acc[i][j] += kv4[i] * vv4[j];
    }
  }
  float* o = kvout + (size_t)bid * (HDIM * HDIM);
  const int dg = d0 >> 3, doff = d0 & 7;
#pragma unroll
  for (int i = 0; i < 4; ++i)
#pragma unroll
    for (int j = 0; j < 4; ++j)
      o[dg * 512 + (e0 + j) * 8 + doff + i] = acc[i][j];  // image layout
  if (e0 == 0) {
#pragma unroll
    for (int i = 0; i < 4; ++i) zkout[(size_t)bid * HDIM + d0 + i] = z[i];
  }
  // V image: slot = sg*64+e, elems j -> v[sg*8+j][e]
  const unsigned short* vsu = (const unsigned short*)vs;
  unsigned short* vo = vimg + (size_t)bid * 8192;
  for (int slot = t; slot < 1024; slot += 256) {
    const int sg = slot >> 6, e = slot & 63;
    ushort4 lo, hi;
    lo.x = vsu[(sg * 8 + 0) * 64 + e]; lo.y = vsu[(sg * 8 + 1) * 64 + e];
    lo.z = vsu[(sg * 8 + 2) * 64 + e]; lo.w = vsu[(sg * 8 + 3) * 64 + e];
    hi.x = vsu[(sg * 8 + 4) * 64 + e]; hi.y = vsu[(sg * 8 + 5) * 64 + e];
    hi.z = vsu[(sg * 8 + 6) * 64 + e]; hi.w = vsu[(sg * 8 + 7) * 64 + e];
    *(ushort4*)&vo[slot * 8] = lo;
    *(ushort4*)&vo[slot * 8 + 4] = hi;
  }
}

// ---------------------------------------------------------------------------
// In-place exclusive prefix over chunks (elementwise; layout-agnostic).
// ---------------------------------------------------------------------------
__global__ __launch_bounds__(256)
void prefix_chunks(float* __restrict__ S, float* __restrict__ Z)
{
  const int bh = blockIdx.x;
  const int t = threadIdx.x;
  float run[16];
#pragma unroll
  for (int j = 0; j < 16; ++j) run[j] = 0.f;
  for (int n = 0; n < NCHUNK; ++n) {
    float* p = S + ((size_t)bh * NCHUNK + n) * (HDIM * HDIM);
#pragma unroll
    for (int j = 0; j < 16; ++j) {
      int idx = t + j * 256;
      float cur = p[idx];
      p[idx] = run[j];
      run[j] += cur;
    }
  }
  if (t < HDIM) {
    float rz = 0.f;
    for (int n = 0; n < NCHUNK; ++n) {
      float* p = Z + ((size_t)bh * NCHUNK + n) * HDIM + t;
      float cur = *p;
      *p = rz;
      rz += cur;
    }
  }
}

// ---------------------------------------------------------------------------
// Barrier-free MFMA chunk_attn. One block per (b,h,n), 4 waves, 1 barrier.
// PT = phik @ phiq^T per-wave (producer==consumer); per-wave private P LDS.
// den = EPS + MFMA(phiq, Zbcast) + MFMA(P, ones) — rows align with num.
// LDS: Vimg 16K + Simg(bf16) 8K + P 17K = ~41 KB -> 3 blocks/CU.
// ---------------------------------------------------------------------------
#define PW_STRIDE 136  // 272 B row stride: 2-way-free banks, 16B aligned

__global__ __launch_bounds__(256, 3)
void chunk_attn(const __hip_bfloat16* __restrict__ Qp,
                const __hip_bfloat16* __restrict__ Kp,
                const unsigned short* __restrict__ vimg,  // [bid][1024 slots][8]
                const float* __restrict__ Simg,           // [bid][4096] image fp32
                const float* __restrict__ Zp,             // [bid][64]
                __hip_bfloat16* __restrict__ Yp)
{
  __shared__ __align__(16) unsigned short VL[8192];             // 16 KB
  __shared__ __align__(16) unsigned short SL[4096];             // 8 KB
  __shared__ __align__(16) unsigned short PL[4 * 16 * PW_STRIDE];  // 17 KB

  const int bid = blockIdx.x;
  const int n = bid & 15, h = (bid >> 4) & 15, b = bid >> 8;
  const int tokbase = b * T_LEN + n * CHUNK_;
  const size_t gbase = (size_t)tokbase * E_DIM + h * HDIM;
  const int t = threadIdx.x, lane = t & 63, wv = t >> 6;
  const int lm = lane & 15, kg = lane >> 4;

  // ---- stage V image (contiguous async) ----
#pragma unroll
  for (int i = 0; i < 4; ++i) {
    const int j = wv * 4 + i;
    gld_lds16(vimg + (size_t)bid * 8192 + (size_t)(j * 64 + lane) * 8,
              (char*)VL + j * 1024);
  }
  // ---- stage S image fp32 -> bf16 (contiguous) ----
#pragma unroll
  for (int i = 0; i < 4; ++i) {
    const int idx = i * 1024 + t * 4;
    float4 s4 = *(const float4*)(Simg + (size_t)bid * 4096 + idx);
    ushort4 o;
    o.x = f2bu(s4.x); o.y = f2bu(s4.y); o.z = f2bu(s4.z); o.w = f2bu(s4.w);
    *(ushort4*)&SL[idx] = o;
  }

  const int mts[2] = { wv, 7 - wv };
  // ---- phiq A/B frags from global (layout identical for A and B) ----
  bf16x8 aq[2][2];
#pragma unroll
  for (int mi = 0; mi < 2; ++mi)
#pragma unroll
    for (int kh = 0; kh < 2; ++kh)
      aq[mi][kh] = *(const bf16x8*)(Qp + gbase +
                    (size_t)(mts[mi] * 16 + lm) * E_DIM + kh * 32 + kg * 8);
  // ---- Z broadcast-B frags (value depends only on k) ----
  bf16x8 zb[2];
#pragma unroll
  for (int kh = 0; kh < 2; ++kh) {
    float4 z0 = *(const float4*)(Zp + (size_t)bid * 64 + kh * 32 + kg * 8);
    float4 z1 = *(const float4*)(Zp + (size_t)bid * 64 + kh * 32 + kg * 8 + 4);
    zb[kh][0] = (short)f2bu(z0.x); zb[kh][1] = (short)f2bu(z0.y);
    zb[kh][2] = (short)f2bu(z0.z); zb[kh][3] = (short)f2bu(z0.w);
    zb[kh][4] = (short)f2bu(z1.x); zb[kh][5] = (short)f2bu(z1.y);
    zb[kh][6] = (short)f2bu(z1.z); zb[kh][7] = (short)f2bu(z1.w);
  }

  __syncthreads();  // the ONLY barrier: all staging (incl. async V) visible

  f32x4 accn[2][4];
  f32x4 accden[2];
#pragma unroll
  for (int mi = 0; mi < 2; ++mi) {
    accden[mi] = (f32x4){EPS_, EPS_, EPS_, EPS_};
#pragma unroll
    for (int ne = 0; ne < 4; ++ne) accn[mi][ne] = (f32x4){0.f, 0.f, 0.f, 0.f};
  }

  // ---- history: num += phiq @ S_prev ; den += phiq . Z ----
#pragma unroll
  for (int mi = 0; mi < 2; ++mi)
#pragma unroll
    for (int kh = 0; kh < 2; ++kh) {
      const bf16x8 a = aq[mi][kh];
      accden[mi] = __builtin_amdgcn_mfma_f32_16x16x32_bf16(a, zb[kh], accden[mi], 0, 0, 0);
#pragma unroll
      for (int ne = 0; ne < 4; ++ne) {
        bf16x8 bs = *(const bf16x8*)&SL[((kh * 4 + kg) * 64 + ne * 16 + lm) * 8];
        accn[mi][ne] = __builtin_amdgcn_mfma_f32_16x16x32_bf16(a, bs, accn[mi][ne], 0, 0, 0);
      }
    }

  // ---- per-wave causal part: PT tiles -> private P LDS -> PV ----
  unsigned short* Pw = PL + wv * 16 * PW_STRIDE;
  bf16x8 ones;
#pragma unroll
  for (int j = 0; j < 8; ++j) ones[j] = (short)0x3F80;

#pragma unroll
  for (int mi = 0; mi < 2; ++mi) {
    const int mt = mts[mi], m0 = mt * 16;
    // PT tiles (s-tile nt, m-cols of tile mt); same wave writes P[m][s]
    for (int nt = 0; nt <= mt; ++nt) {
      f32x4 pt = (f32x4){0.f, 0.f, 0.f, 0.f};
#pragma unroll
      for (int kh = 0; kh < 2; ++kh) {
        bf16x8 ak = *(const bf16x8*)(Kp + gbase +
                     (size_t)(nt * 16 + lm) * E_DIM + kh * 32 + kg * 8);
        pt = __builtin_amdgcn_mfma_f32_16x16x32_bf16(ak, aq[mi][kh], pt, 0, 0, 0);
      }
      unsigned short u[4];
#pragma unroll
      for (int r = 0; r < 4; ++r) {
        float v = pt[r];
        if (nt == mt) {  // diagonal: rows s_local=kg*4+r, cols m_local=lm; keep s<=m
          v = ((kg * 4 + r) <= lm) ? v : 0.f;
        }
        u[r] = f2bu(v);
      }
      const int sidx = lm * PW_STRIDE + nt * 16 + kg * 4;
      *(unsigned*)&Pw[sidx]     = (unsigned)u[0] | ((unsigned)u[1] << 16);
      *(unsigned*)&Pw[sidx + 2] = (unsigned)u[2] | ((unsigned)u[3] << 16);
    }
    // zero-fill to 32-boundary for even mt
    if ((mt & 1) == 0 && lane < 32) {
      const int m = lane >> 1, half = lane & 1;
      *(uint4*)&Pw[m * PW_STRIDE + (mt + 1) * 16 + half * 8] = (uint4){0u, 0u, 0u, 0u};
    }
    // PV + rowsum(P)
    const int ktc = (mt + 2) >> 1;
    for (int kt = 0; kt < ktc; ++kt) {
      bf16x8 ap = *(const bf16x8*)&Pw[lm * PW_STRIDE + kt * 32 + kg * 8];
      accden[mi] = __builtin_amdgcn_mfma_f32_16x16x32_bf16(ap, ones, accden[mi], 0, 0, 0);
#pragma unroll
      for (int ne = 0; ne < 4; ++ne) {
        bf16x8 bv = *(const bf16x8*)&VL[((kt * 4 + kg) * 64 + ne * 16 + lm) * 8];
        accn[mi][ne] = __builtin_amdgcn_mfma_f32_16x16x32_bf16(ap, bv, accn[mi][ne], 0, 0, 0);
      }
    }
  }

  // ---- epilogue: y = num / den (accden rows == accn rows) ----
#pragma unroll
  for (int mi = 0; mi < 2; ++mi) {
    const int m0 = mts[mi] * 16;
    float inv[4];
#pragma unroll
    for (int r = 0; r < 4; ++r) inv[r] = 1.f / accden[mi][r];
#pragma unroll
    for (int ne = 0; ne < 4; ++ne) {
      const int col = h * HDIM + ne * 16 + lm;
#pragma unroll
      for (int r = 0; r < 4; ++r) {
        const int row = tokbase + m0 + kg * 4 + r;
        Yp[(size_t)row * E_DIM + col] = __float2bfloat16(accn[mi][ne][r] * inv[r]);
      }
    }
  }
}

// ---------------------------------------------------------------------------
extern "C" void kernel_launch(void* const* d_in, const int* in_sizes, int n_in,
                              void* d_out, int out_size, void* d_ws, size_t ws_size,
                              hipStream_t stream)
{
  const float* x  = (const float*)d_in[0];
  const float* Wq = (const float*)d_in[1];
  const float* Wk = (const float*)d_in[2];
  const float* Wv = (const float*)d_in[3];
  const float* Wp = (const float*)d_in[4];
  const float* bp = (const float*)d_in[5];
  float* out = (float*)d_out;

  const size_t MT = (size_t)BATCH * T_LEN;  // 8192 rows
  char* w = (char*)d_ws;
  __hip_bfloat16* xb  = (__hip_bfloat16*)w; w += MT * E_DIM * sizeof(__hip_bfloat16);
  __hip_bfloat16* Wqb = (__hip_bfloat16*)w; w += (size_t)E_DIM * E_DIM * sizeof(__hip_bfloat16);
  __hip_bfloat16* Wkb = (__hip_bfloat16*)w; w += (size_t)E_DIM * E_DIM * sizeof(__hip_bfloat16);
  __hip_bfloat16* Wvb = (__hip_bfloat16*)w; w += (size_t)E_DIM * E_DIM * sizeof(__hip_bfloat16);
  __hip_bfloat16* Wpb = (__hip_bfloat16*)w; w += (size_t)E_DIM * E_DIM * sizeof(__hip_bfloat16);
  __hip_bfloat16* q = (__hip_bfloat16*)w; w += MT * E_DIM * sizeof(__hip_bfloat16);
  __hip_bfloat16* k = (__hip_bfloat16*)w; w += MT * E_DIM * sizeof(__hip_bfloat16);
  __hip_bfloat16* v = (__hip_bfloat16*)w; w += MT * E_DIM * sizeof(__hip_bfloat16);
  __hip_bfloat16* y = (__hip_bfloat16*)w; w += MT * E_DIM * sizeof(__hip_bfloat16);
  float* S = (float*)w; w += (size_t)BATCH * HEADS * NCHUNK * HDIM * HDIM * sizeof(float);
  float* Z = (float*)w; w += (size_t)BATCH * HEADS * NCHUNK * HDIM * sizeof(float);
  // V image reuses xb (dead after gemm_qkv; chunk_kv runs strictly after)
  unsigned short* vimg = (unsigned short*)xb;

  cast5<<<8192 + 4096, 256, 0, stream>>>(x, Wq, Wk, Wv, Wp, xb, Wqb, Wkb, Wvb, Wpb);
  gemm_qkv<<<dim3(MT / 128, 24), 256, 0, stream>>>(xb, Wqb, Wkb, Wvb, q, k, v);
  chunk_kv<<<BATCH * HEADS * NCHUNK, 256, 0, stream>>>(k, v, S, Z, vimg);
  prefix_chunks<<<BATCH * HEADS, 256, 0, stream>>>(S, Z);
  chunk_attn<<<BATCH * HEADS * NCHUNK, 256, 0, stream>>>(q, k, vimg, S, Z, y);
  gemm_out<<<dim3(MT / 128, 8), 256, 0, stream>>>(y, Wpb, bp, out);
}

// Round 7
// 245.451 us; speedup vs baseline: 1.8445x; 1.0090x over previous
//
#include <hip/hip_runtime.h>
#include <hip/hip_bf16.h>
#include <stdint.h>

#define T_LEN  2048
#define E_DIM  1024
#define BATCH  4
#define HEADS  16
#define HDIM   64
#define CHUNK_ 128
#define NCHUNK 16
#define EPS_   1e-6f

typedef __attribute__((ext_vector_type(8))) short bf16x8;
typedef __attribute__((ext_vector_type(4))) float f32x4;

__device__ __forceinline__ float b2f(__hip_bfloat16 h) { return __bfloat162float(h); }
__device__ __forceinline__ unsigned short f2bu(float f) {
  __hip_bfloat16 h = __float2bfloat16(f);
  return *(unsigned short*)&h;
}
// async global->LDS, 16B per lane; LDS dest = base + lane*16 (wave-uniform base)
__device__ __forceinline__ void gld_lds16(const void* g, void* l) {
  __builtin_amdgcn_global_load_lds((const __attribute__((address_space(1))) void*)g,
                                   (__attribute__((address_space(3))) void*)l,
                                   16, 0, 0);
}

// ---------------------------------------------------------------------------
// fp32 -> bf16 cast for x (8192x1024) and four 1024x1024 weights.
// ---------------------------------------------------------------------------
__global__ __launch_bounds__(256)
void cast5(const float* __restrict__ x,  const float* __restrict__ w0,
           const float* __restrict__ w1, const float* __restrict__ w2,
           const float* __restrict__ w3,
           __hip_bfloat16* __restrict__ xb,  __hip_bfloat16* __restrict__ w0b,
           __hip_bfloat16* __restrict__ w1b, __hip_bfloat16* __restrict__ w2b,
           __hip_bfloat16* __restrict__ w3b)
{
  const int b = blockIdx.x;
  const float* s;
  __hip_bfloat16* d;
  size_t off;
  if (b < 8192) { s = x; d = xb; off = (size_t)b * 1024; }
  else {
    const int i = (b - 8192) >> 10;
    const int r = (b - 8192) & 1023;
    s = (i == 0) ? w0 : (i == 1) ? w1 : (i == 2) ? w2 : w3;
    d = (i == 0) ? w0b : (i == 1) ? w1b : (i == 2) ? w2b : w3b;
    off = (size_t)r * 1024;
  }
  const int t = threadIdx.x;
  float4 v = *(const float4*)(s + off + (size_t)t * 4);
  ushort4 o;
  o.x = f2bu(v.x); o.y = f2bu(v.y); o.z = f2bu(v.z); o.w = f2bu(v.w);
  *(ushort4*)((unsigned short*)d + off + (size_t)t * 4) = o;
}

// ---------------------------------------------------------------------------
// 128x128 GEMM core (m97 structure): BK=32, global_load_lds width=16,
// LDS row-major [m][32k] (64B rows), wave w owns 64x64 quadrant.
// ---------------------------------------------------------------------------
__device__ __forceinline__ void gemm128_core(
    const __hip_bfloat16* __restrict__ X,
    const __hip_bfloat16* __restrict__ W,
    int bm, int bn, f32x4 acc[4][4],
    __hip_bfloat16* Xs, __hip_bfloat16* Ws)
{
  const int t = threadIdx.x, lane = t & 63, wave = t >> 6;
  const int wm = (wave >> 1) * 64, wn = (wave & 1) * 64;
  for (int k0 = 0; k0 < 1024; k0 += 32) {
    if (k0) __syncthreads();
#pragma unroll
    for (int i = 0; i < 2; ++i) {
      const int j = wave * 2 + i;
      const int m = j * 16 + (lane >> 2);
      const int kg = lane & 3;
      gld_lds16(X + (size_t)(bm * 128 + m) * 1024 + k0 + kg * 8, (char*)Xs + j * 1024);
      gld_lds16(W + (size_t)(bn * 128 + m) * 1024 + k0 + kg * 8, (char*)Ws + j * 1024);
    }
    __syncthreads();
    bf16x8 a[4], b[4];
#pragma unroll
    for (int i = 0; i < 4; ++i) {
      a[i] = *(const bf16x8*)&Xs[((wm + i * 16 + (lane & 15)) * 4 + (lane >> 4)) * 8];
      b[i] = *(const bf16x8*)&Ws[((wn + i * 16 + (lane & 15)) * 4 + (lane >> 4)) * 8];
    }
#pragma unroll
    for (int i = 0; i < 4; ++i)
#pragma unroll
      for (int jn = 0; jn < 4; ++jn)
        acc[i][jn] = __builtin_amdgcn_mfma_f32_16x16x32_bf16(a[i], b[jn], acc[i][jn], 0, 0, 0);
  }
}

// fused q/k/v projection: grid (64, 24); bn>>3 selects {q,k,v}
__global__ __launch_bounds__(256, 2)
void gemm_qkv(const __hip_bfloat16* __restrict__ X,
              const __hip_bfloat16* __restrict__ Wq,
              const __hip_bfloat16* __restrict__ Wk,
              const __hip_bfloat16* __restrict__ Wv,
              __hip_bfloat16* __restrict__ qo,
              __hip_bfloat16* __restrict__ ko,
              __hip_bfloat16* __restrict__ vo)
{
  __shared__ __align__(16) __hip_bfloat16 Xs[128 * 32];
  __shared__ __align__(16) __hip_bfloat16 Ws[128 * 32];
  const int bm = blockIdx.x, bnx = blockIdx.y;
  const int which = bnx >> 3, bn = bnx & 7;
  const __hip_bfloat16* W = (which == 0) ? Wq : (which == 1) ? Wk : Wv;
  __hip_bfloat16* C = (which == 0) ? qo : (which == 1) ? ko : vo;
  const bool elu = (which < 2);
  f32x4 acc[4][4];
#pragma unroll
  for (int i = 0; i < 4; ++i)
#pragma unroll
    for (int j = 0; j < 4; ++j) acc[i][j] = (f32x4){0.f, 0.f, 0.f, 0.f};
  gemm128_core(X, W, bm, bn, acc, Xs, Ws);
  const int lane = threadIdx.x & 63, wave = threadIdx.x >> 6;
  const int wm = (wave >> 1) * 64, wn = (wave & 1) * 64;
  const int r0 = (lane >> 4) * 4;
#pragma unroll
  for (int mi = 0; mi < 4; ++mi)
#pragma unroll
    for (int ni = 0; ni < 4; ++ni) {
      const int row = bm * 128 + wm + mi * 16 + r0;
      const int col = bn * 128 + wn + ni * 16 + (lane & 15);
#pragma unroll
      for (int r = 0; r < 4; ++r) {
        float v = acc[mi][ni][r];
        if (elu) v = (v > 0.f) ? (v + 1.f) : __expf(v);
        C[(size_t)(row + r) * 1024 + col] = __float2bfloat16(v);
      }
    }
}

// output projection: fp32 out + bias; grid (64, 8)
__global__ __launch_bounds__(256, 2)
void gemm_out(const __hip_bfloat16* __restrict__ X,
              const __hip_bfloat16* __restrict__ W,
              const float* __restrict__ bias,
              float* __restrict__ C)
{
  __shared__ __align__(16) __hip_bfloat16 Xs[128 * 32];
  __shared__ __align__(16) __hip_bfloat16 Ws[128 * 32];
  const int bm = blockIdx.x, bn = blockIdx.y;
  f32x4 acc[4][4];
#pragma unroll
  for (int i = 0; i < 4; ++i)
#pragma unroll
    for (int j = 0; j < 4; ++j) acc[i][j] = (f32x4){0.f, 0.f, 0.f, 0.f};
  gemm128_core(X, W, bm, bn, acc, Xs, Ws);
  const int lane = threadIdx.x & 63, wave = threadIdx.x >> 6;
  const int wm = (wave >> 1) * 64, wn = (wave & 1) * 64;
  const int r0 = (lane >> 4) * 4;
#pragma unroll
  for (int mi = 0; mi < 4; ++mi)
#pragma unroll
    for (int ni = 0; ni < 4; ++ni) {
      const int row = bm * 128 + wm + mi * 16 + r0;
      const int col = bn * 128 + wn + ni * 16 + (lane & 15);
      const float bv = bias[col];
#pragma unroll
      for (int r = 0; r < 4; ++r)
        C[(size_t)(row + r) * 1024 + col] = acc[mi][ni][r] + bv;
    }
}

// ---------------------------------------------------------------------------
// Per-chunk KV state in B-frag IMAGE layout (round-4 verified VALU version):
//   Simg flat idx = (d>>3)*512 + e*8 + (d&7)  (fp32, prefix-summed later)
// Also emits V image: vimg[bid][sg*64+e][j] = v[sg*8+j][e] (bf16).
// ---------------------------------------------------------------------------
__global__ __launch_bounds__(256)
void chunk_kv(const __hip_bfloat16* __restrict__ Kp,
              const __hip_bfloat16* __restrict__ Vp,
              float* __restrict__ kvout, float* __restrict__ zkout,
              unsigned short* __restrict__ vimg)
{
  const int bid = blockIdx.x;  // b*256 + h*16 + n
  const int n = bid & 15, h = (bid >> 4) & 15, b = bid >> 8;
  __shared__ __align__(16) __hip_bfloat16 ks[CHUNK_ * HDIM];
  __shared__ __align__(16) __hip_bfloat16 vs[CHUNK_ * HDIM];
  const size_t base = ((size_t)(b * T_LEN + n * CHUNK_)) * E_DIM + h * HDIM;
  const int t = threadIdx.x;
  for (int i = t; i < CHUNK_ * 8; i += 256) {
    int r = i >> 3, c = (i & 7) << 3;
    *(uint4*)&ks[r * HDIM + c] = *(const uint4*)(Kp + base + (size_t)r * E_DIM + c);
    *(uint4*)&vs[r * HDIM + c] = *(const uint4*)(Vp + base + (size_t)r * E_DIM + c);
  }
  __syncthreads();
  const int d0 = (t >> 4) << 2, e0 = (t & 15) << 2;
  float acc[4][4] = {{0.f}};
  float z[4] = {0.f, 0.f, 0.f, 0.f};
  for (int c = 0; c < CHUNK_; ++c) {
    float kv4[4], vv4[4];
#pragma unroll
    for (int i = 0; i < 4; ++i) kv4[i] = b2f(ks[c * HDIM + d0 + i]);
#pragma unroll
    for (int j = 0; j < 4; ++j) vv4[j] = b2f(vs[c * HDIM + e0 + j]);
#pragma unroll
    for (int i = 0; i < 4; ++i) {
      z[i] += kv4[i];
#pragma unroll
      for (int j = 0; j < 4; ++j) acc[i][j] += kv4[i] * vv4[j];
    }
  }
  float* o = kvout + (size_t)bid * (HDIM * HDIM);
  const int dg = d0 >> 3, doff = d0 & 7;
#pragma unroll
  for (int i = 0; i < 4; ++i)
#pragma unroll
    for (int j = 0; j < 4; ++j)
      o[dg * 512 + (e0 + j) * 8 + doff + i] = acc[i][j];  // image layout
  if (e0 == 0) {
#pragma unroll
    for (int i = 0; i < 4; ++i) zkout[(size_t)bid * HDIM + d0 + i] = z[i];
  }
  // V image: slot = sg*64+e, elems j -> v[sg*8+j][e]
  const unsigned short* vsu = (const unsigned short*)vs;
  unsigned short* vo = vimg + (size_t)bid * 8192;
  for (int slot = t; slot < 1024; slot += 256) {
    const int sg = slot >> 6, e = slot & 63;
    ushort4 lo, hi;
    lo.x = vsu[(sg * 8 + 0) * 64 + e]; lo.y = vsu[(sg * 8 + 1) * 64 + e];
    lo.z = vsu[(sg * 8 + 2) * 64 + e]; lo.w = vsu[(sg * 8 + 3) * 64 + e];
    hi.x = vsu[(sg * 8 + 4) * 64 + e]; hi.y = vsu[(sg * 8 + 5) * 64 + e];
    hi.z = vsu[(sg * 8 + 6) * 64 + e]; hi.w = vsu[(sg * 8 + 7) * 64 + e];
    *(ushort4*)&vo[slot * 8] = lo;
    *(ushort4*)&vo[slot * 8 + 4] = hi;
  }
}

// ---------------------------------------------------------------------------
// In-place exclusive prefix over chunks (elementwise; layout-agnostic).
// ---------------------------------------------------------------------------
__global__ __launch_bounds__(256)
void prefix_chunks(float* __restrict__ S, float* __restrict__ Z)
{
  const int bh = blockIdx.x;
  const int t = threadIdx.x;
  float run[16];
#pragma unroll
  for (int j = 0; j < 16; ++j) run[j] = 0.f;
  for (int n = 0; n < NCHUNK; ++n) {
    float* p = S + ((size_t)bh * NCHUNK + n) * (HDIM * HDIM);
#pragma unroll
    for (int j = 0; j < 16; ++j) {
      int idx = t + j * 256;
      float cur = p[idx];
      p[idx] = run[j];
      run[j] += cur;
    }
  }
  if (t < HDIM) {
    float rz = 0.f;
    for (int n = 0; n < NCHUNK; ++n) {
      float* p = Z + ((size_t)bh * NCHUNK + n) * HDIM + t;
      float cur = *p;
      *p = rz;
      rz += cur;
    }
  }
}

// ---------------------------------------------------------------------------
// Barrier-free MFMA chunk_attn (round-4 verified).
// ---------------------------------------------------------------------------
#define PW_STRIDE 136  // 272 B row stride: 2-way-free banks, 16B aligned

__global__ __launch_bounds__(256, 3)
void chunk_attn(const __hip_bfloat16* __restrict__ Qp,
                const __hip_bfloat16* __restrict__ Kp,
                const unsigned short* __restrict__ vimg,  // [bid][1024 slots][8]
                const float* __restrict__ Simg,           // [bid][4096] image fp32
                const float* __restrict__ Zp,             // [bid][64]
                __hip_bfloat16* __restrict__ Yp)
{
  __shared__ __align__(16) unsigned short VL[8192];             // 16 KB
  __shared__ __align__(16) unsigned short SL[4096];             // 8 KB
  __shared__ __align__(16) unsigned short PL[4 * 16 * PW_STRIDE];  // 17 KB

  const int bid = blockIdx.x;
  const int n = bid & 15, h = (bid >> 4) & 15, b = bid >> 8;
  const int tokbase = b * T_LEN + n * CHUNK_;
  const size_t gbase = (size_t)tokbase * E_DIM + h * HDIM;
  const int t = threadIdx.x, lane = t & 63, wv = t >> 6;
  const int lm = lane & 15, kg = lane >> 4;

  // ---- stage V image (contiguous async) ----
#pragma unroll
  for (int i = 0; i < 4; ++i) {
    const int j = wv * 4 + i;
    gld_lds16(vimg + (size_t)bid * 8192 + (size_t)(j * 64 + lane) * 8,
              (char*)VL + j * 1024);
  }
  // ---- stage S image fp32 -> bf16 (contiguous) ----
#pragma unroll
  for (int i = 0; i < 4; ++i) {
    const int idx = i * 1024 + t * 4;
    float4 s4 = *(const float4*)(Simg + (size_t)bid * 4096 + idx);
    ushort4 o;
    o.x = f2bu(s4.x); o.y = f2bu(s4.y); o.z = f2bu(s4.z); o.w = f2bu(s4.w);
    *(ushort4*)&SL[idx] = o;
  }

  const int mts[2] = { wv, 7 - wv };
  // ---- phiq A/B frags from global (layout identical for A and B) ----
  bf16x8 aq[2][2];
#pragma unroll
  for (int mi = 0; mi < 2; ++mi)
#pragma unroll
    for (int kh = 0; kh < 2; ++kh)
      aq[mi][kh] = *(const bf16x8*)(Qp + gbase +
                    (size_t)(mts[mi] * 16 + lm) * E_DIM + kh * 32 + kg * 8);
  // ---- Z broadcast-B frags (value depends only on k) ----
  bf16x8 zb[2];
#pragma unroll
  for (int kh = 0; kh < 2; ++kh) {
    float4 z0 = *(const float4*)(Zp + (size_t)bid * 64 + kh * 32 + kg * 8);
    float4 z1 = *(const float4*)(Zp + (size_t)bid * 64 + kh * 32 + kg * 8 + 4);
    zb[kh][0] = (short)f2bu(z0.x); zb[kh][1] = (short)f2bu(z0.y);
    zb[kh][2] = (short)f2bu(z0.z); zb[kh][3] = (short)f2bu(z0.w);
    zb[kh][4] = (short)f2bu(z1.x); zb[kh][5] = (short)f2bu(z1.y);
    zb[kh][6] = (short)f2bu(z1.z); zb[kh][7] = (short)f2bu(z1.w);
  }

  __syncthreads();  // the ONLY barrier: all staging (incl. async V) visible

  f32x4 accn[2][4];
  f32x4 accden[2];
#pragma unroll
  for (int mi = 0; mi < 2; ++mi) {
    accden[mi] = (f32x4){EPS_, EPS_, EPS_, EPS_};
#pragma unroll
    for (int ne = 0; ne < 4; ++ne) accn[mi][ne] = (f32x4){0.f, 0.f, 0.f, 0.f};
  }

  // ---- history: num += phiq @ S_prev ; den += phiq . Z ----
#pragma unroll
  for (int mi = 0; mi < 2; ++mi)
#pragma unroll
    for (int kh = 0; kh < 2; ++kh) {
      const bf16x8 a = aq[mi][kh];
      accden[mi] = __builtin_amdgcn_mfma_f32_16x16x32_bf16(a, zb[kh], accden[mi], 0, 0, 0);
#pragma unroll
      for (int ne = 0; ne < 4; ++ne) {
        bf16x8 bs = *(const bf16x8*)&SL[((kh * 4 + kg) * 64 + ne * 16 + lm) * 8];
        accn[mi][ne] = __builtin_amdgcn_mfma_f32_16x16x32_bf16(a, bs, accn[mi][ne], 0, 0, 0);
      }
    }

  // ---- per-wave causal part: PT tiles -> private P LDS -> PV ----
  unsigned short* Pw = PL + wv * 16 * PW_STRIDE;
  bf16x8 ones;
#pragma unroll
  for (int j = 0; j < 8; ++j) ones[j] = (short)0x3F80;

#pragma unroll
  for (int mi = 0; mi < 2; ++mi) {
    const int mt = mts[mi], m0 = mt * 16;
    // PT tiles (s-tile nt, m-cols of tile mt); same wave writes P[m][s]
    for (int nt = 0; nt <= mt; ++nt) {
      f32x4 pt = (f32x4){0.f, 0.f, 0.f, 0.f};
#pragma unroll
      for (int kh = 0; kh < 2; ++kh) {
        bf16x8 ak = *(const bf16x8*)(Kp + gbase +
                     (size_t)(nt * 16 + lm) * E_DIM + kh * 32 + kg * 8);
        pt = __builtin_amdgcn_mfma_f32_16x16x32_bf16(ak, aq[mi][kh], pt, 0, 0, 0);
      }
      unsigned short u[4];
#pragma unroll
      for (int r = 0; r < 4; ++r) {
        float v = pt[r];
        if (nt == mt) {  // diagonal: rows s_local=kg*4+r, cols m_local=lm; keep s<=m
          v = ((kg * 4 + r) <= lm) ? v : 0.f;
        }
        u[r] = f2bu(v);
      }
      const int sidx = lm * PW_STRIDE + nt * 16 + kg * 4;
      *(unsigned*)&Pw[sidx]     = (unsigned)u[0] | ((unsigned)u[1] << 16);
      *(unsigned*)&Pw[sidx + 2] = (unsigned)u[2] | ((unsigned)u[3] << 16);
    }
    // zero-fill to 32-boundary for even mt
    if ((mt & 1) == 0 && lane < 32) {
      const int m = lane >> 1, half = lane & 1;
      *(uint4*)&Pw[m * PW_STRIDE + (mt + 1) * 16 + half * 8] = (uint4){0u, 0u, 0u, 0u};
    }
    // PV + rowsum(P)
    const int ktc = (mt + 2) >> 1;
    for (int kt = 0; kt < ktc; ++kt) {
      bf16x8 ap = *(const bf16x8*)&Pw[lm * PW_STRIDE + kt * 32 + kg * 8];
      accden[mi] = __builtin_amdgcn_mfma_f32_16x16x32_bf16(ap, ones, accden[mi], 0, 0, 0);
#pragma unroll
      for (int ne = 0; ne < 4; ++ne) {
        bf16x8 bv = *(const bf16x8*)&VL[((kt * 4 + kg) * 64 + ne * 16 + lm) * 8];
        accn[mi][ne] = __builtin_amdgcn_mfma_f32_16x16x32_bf16(ap, bv, accn[mi][ne], 0, 0, 0);
      }
    }
  }

  // ---- epilogue: y = num / den (accden rows == accn rows) ----
#pragma unroll
  for (int mi = 0; mi < 2; ++mi) {
    const int m0 = mts[mi] * 16;
    float inv[4];
#pragma unroll
    for (int r = 0; r < 4; ++r) inv[r] = 1.f / accden[mi][r];
#pragma unroll
    for (int ne = 0; ne < 4; ++ne) {
      const int col = h * HDIM + ne * 16 + lm;
#pragma unroll
      for (int r = 0; r < 4; ++r) {
        const int row = tokbase + m0 + kg * 4 + r;
        Yp[(size_t)row * E_DIM + col] = __float2bfloat16(accn[mi][ne][r] * inv[r]);
      }
    }
  }
}

// ---------------------------------------------------------------------------
extern "C" void kernel_launch(void* const* d_in, const int* in_sizes, int n_in,
                              void* d_out, int out_size, void* d_ws, size_t ws_size,
                              hipStream_t stream)
{
  const float* x  = (const float*)d_in[0];
  const float* Wq = (const float*)d_in[1];
  const float* Wk = (const float*)d_in[2];
  const float* Wv = (const float*)d_in[3];
  const float* Wp = (const float*)d_in[4];
  const float* bp = (const float*)d_in[5];
  float* out = (float*)d_out;

  const size_t MT = (size_t)BATCH * T_LEN;  // 8192 rows
  char* w = (char*)d_ws;
  __hip_bfloat16* xb  = (__hip_bfloat16*)w; w += MT * E_DIM * sizeof(__hip_bfloat16);
  __hip_bfloat16* Wqb = (__hip_bfloat16*)w; w += (size_t)E_DIM * E_DIM * sizeof(__hip_bfloat16);
  __hip_bfloat16* Wkb = (__hip_bfloat16*)w; w += (size_t)E_DIM * E_DIM * sizeof(__hip_bfloat16);
  __hip_bfloat16* Wvb = (__hip_bfloat16*)w; w += (size_t)E_DIM * E_DIM * sizeof(__hip_bfloat16);
  __hip_bfloat16* Wpb = (__hip_bfloat16*)w; w += (size_t)E_DIM * E_DIM * sizeof(__hip_bfloat16);
  __hip_bfloat16* q = (__hip_bfloat16*)w; w += MT * E_DIM * sizeof(__hip_bfloat16);
  __hip_bfloat16* k = (__hip_bfloat16*)w; w += MT * E_DIM * sizeof(__hip_bfloat16);
  __hip_bfloat16* v = (__hip_bfloat16*)w; w += MT * E_DIM * sizeof(__hip_bfloat16);
  __hip_bfloat16* y = (__hip_bfloat16*)w; w += MT * E_DIM * sizeof(__hip_bfloat16);
  float* S = (float*)w; w += (size_t)BATCH * HEADS * NCHUNK * HDIM * HDIM * sizeof(float);
  float* Z = (float*)w; w += (size_t)BATCH * HEADS * NCHUNK * HDIM * sizeof(float);
  // V image reuses xb (dead after gemm_qkv; chunk_kv runs strictly after)
  unsigned short* vimg = (unsigned short*)xb;

  cast5<<<8192 + 4096, 256, 0, stream>>>(x, Wq, Wk, Wv, Wp, xb, Wqb, Wkb, Wvb, Wpb);
  gemm_qkv<<<dim3(MT / 128, 24), 256, 0, stream>>>(xb, Wqb, Wkb, Wvb, q, k, v);
  chunk_kv<<<BATCH * HEADS * NCHUNK, 256, 0, stream>>>(k, v, S, Z, vimg);
  prefix_chunks<<<BATCH * HEADS, 256, 0, stream>>>(S, Z);
  chunk_attn<<<BATCH * HEADS * NCHUNK, 256, 0, stream>>>(q, k, vimg, S, Z, y);
  gemm_out<<<dim3(MT / 128, 8), 256, 0, stream>>>(y, Wpb, bp, out);
}